// Round 3
// baseline (439.647 us; speedup 1.0000x reference)
//
#include <hip/hip_runtime.h>

#define NN 10000
#define DIN 128
#define HD 64
#define HH 128          // H*HEADS
#define NE 250000
#define NP 100000
#define P1_BLOCKS 2500

// ---------------- CSR build ----------------

__global__ void count_kernel(const int* e12, const int* e21, int* cnt12, int* cnt21) {
    int t = blockIdx.x * blockDim.x + threadIdx.x;
    if (t < NE)            atomicAdd(&cnt12[e12[NE + t]], 1);
    else if (t < 2 * NE)   atomicAdd(&cnt21[e21[NE + (t - NE)]], 1);
}

__global__ void scan_kernel(const int* cnt12, const int* cnt21,
                            int* ptr12, int* ptr21, int* cur12, int* cur21) {
    const int* cnt = blockIdx.x ? cnt21 : cnt12;
    int* ptr = blockIdx.x ? ptr21 : ptr12;
    int* cur = blockIdx.x ? cur21 : cur12;
    const int T = 1024, C = 10;                 // 1024*10 = 10240 >= 10000
    __shared__ int sm[1024];
    int t = threadIdx.x;
    int v[C]; int tot = 0;
    int base = t * C;
    #pragma unroll
    for (int i = 0; i < C; i++) {
        int id = base + i;
        v[i] = (id < NN) ? cnt[id] : 0;
        tot += v[i];
    }
    sm[t] = tot; __syncthreads();
    for (int off = 1; off < T; off <<= 1) {
        int x = (t >= off) ? sm[t - off] : 0;
        __syncthreads();
        sm[t] += x;
        __syncthreads();
    }
    int run = sm[t] - tot;                      // exclusive prefix
    #pragma unroll
    for (int i = 0; i < C; i++) {
        int id = base + i;
        if (id < NN) { ptr[id] = run; cur[id] = run; }
        run += v[i];
    }
    if (t == T - 1) ptr[NN] = run;
}

// writes rows_sorted directly: no idx indirection in the hot loops
__global__ void fill_kernel(const int* e12, const int* e21,
                            int* cur12, int* cur21, int* rs12, int* rs21) {
    int t = blockIdx.x * blockDim.x + threadIdx.x;
    if (t < NE) {
        int c = e12[NE + t];
        int p = atomicAdd(&cur12[c], 1);
        rs12[p] = e12[t];
    } else if (t < 2 * NE) {
        int e = t - NE;
        int c = e21[NE + e];
        int p = atomicAdd(&cur21[c], 1);
        rs21[p] = e21[e];
    }
}

// ---------------- GEMMs ----------------

// x = relu(xn @ Win[z] + b_in[z]); [10000,128]@[128,64]
__global__ void in_gemm(const float* __restrict__ xn1, const float* __restrict__ xn2,
                        const float* __restrict__ Win, const float* __restrict__ b_in,
                        float* x1, float* x2) {
    int z = blockIdx.z;
    const float4* A4 = (const float4*)(z ? xn2 : xn1);
    const float4* W4 = (const float4*)(Win + (size_t)z * DIN * HD);
    const float4* b4 = (const float4*)(b_in + (size_t)z * HD);
    float4* O4 = (float4*)(z ? x2 : x1);
    __shared__ float As[16 * DIN];
    int tid = threadIdx.x;
    int row0 = blockIdx.x * 16;
    float4* As4 = (float4*)As;
    As4[tid]       = A4[(size_t)row0 * 32 + tid];
    As4[tid + 256] = A4[(size_t)row0 * 32 + tid + 256];
    __syncthreads();
    int r = tid >> 4, cg = tid & 15;
    float4 acc = b4[cg];
    const float* a = &As[r * DIN];
    for (int k = 0; k < DIN; k++) {
        float av = a[k];
        float4 w = W4[k * 16 + cg];
        acc.x += av * w.x; acc.y += av * w.y; acc.z += av * w.z; acc.w += av * w.w;
    }
    acc.x = fmaxf(acc.x, 0.f); acc.y = fmaxf(acc.y, 0.f);
    acc.z = fmaxf(acc.z, 0.f); acc.w = fmaxf(acc.w, 0.f);
    O4[(size_t)(row0 + r) * 16 + cg] = acc;
}

// K/Q/V for BOTH relations: z in [0,6): rel = z/3, kind = z%3 (0=K 1=Q 2=V)
// [10000,64]@[64,128]; block: 8 rows x 128 cols. Also zeroes this layer's sums.
__global__ void kqv_gemm(const float* __restrict__ x1, const float* __restrict__ x2,
                         const float* __restrict__ Wk, const float* __restrict__ Wq,
                         const float* __restrict__ Wv,
                         const float* __restrict__ bk, const float* __restrict__ bq,
                         const float* __restrict__ bv,
                         float* Kb, float* Qb, float* Vb, float* sums, int l) {
    int z = blockIdx.z;
    int rel = z / 3, kind = z - rel * 3;
    if (z == 0 && blockIdx.x == 0 && threadIdx.x < 4) sums[l * 4 + threadIdx.x] = 0.f;
    const float* xsrc = rel ? x2 : x1;
    const float* xdst = rel ? x1 : x2;
    const float* A = (kind == 1) ? xdst : xsrc;
    size_t wo = (size_t)(l * 2 + rel) * HD * HH;
    size_t bo = (size_t)(l * 2 + rel) * HH;
    const float4* W4 = (const float4*)((kind == 0 ? Wk : kind == 1 ? Wq : Wv) + wo);
    const float4* b4 = (const float4*)((kind == 0 ? bk : kind == 1 ? bq : bv) + bo);
    float4* O4 = (float4*)((kind == 0 ? Kb : kind == 1 ? Qb : Vb) + (size_t)rel * NN * HH);
    const float4* A4 = (const float4*)A;
    __shared__ float As[8 * HD];
    int tid = threadIdx.x;
    int row0 = blockIdx.x * 8;
    if (tid < 128) ((float4*)As)[tid] = A4[(size_t)row0 * 16 + tid];
    __syncthreads();
    int r = tid >> 5, cg = tid & 31;
    float4 acc = b4[cg];
    const float* a = &As[r * HD];
    for (int k = 0; k < HD; k++) {
        float av = a[k];
        float4 w = W4[k * 32 + cg];
        acc.x += av * w.x; acc.y += av * w.y; acc.z += av * w.z; acc.w += av * w.w;
    }
    O4[(size_t)(row0 + r) * 32 + cg] = acc;
}

// x_new = (agg * softmax_scale) @ Wout + bout; scale (1/sum) folded into LDS staging.
// z: 0 -> x1 (from rel1 aggregate), 1 -> x2 (from rel0 aggregate)
__global__ void out_gemm(const float* __restrict__ aggb,
                         const float* __restrict__ Wout, const float* __restrict__ bout,
                         const float* __restrict__ sums, int l,
                         float* x1, float* x2, float* Em, float* Ed) {
    int z = blockIdx.z;
    int sel = z ? 0 : 1;                        // which relation's aggregate
    const float4* A4 = (const float4*)(aggb + (size_t)sel * NN * HH);
    const float4* W4 = (const float4*)(Wout + (size_t)(l * 2 + z) * HH * HD);
    const float4* b4 = (const float4*)(bout + (size_t)(l * 2 + z) * HD);
    float inv0 = 1.f / sums[l * 4 + sel * 2 + 0];
    float inv1 = 1.f / sums[l * 4 + sel * 2 + 1];
    float4* X4 = (float4*)(z ? x2 : x1);
    float4* E4 = (float4*)(z ? Ed : Em);
    __shared__ float As[16 * HH];
    int tid = threadIdx.x;
    int row0 = blockIdx.x * 16;
    float4* As4 = (float4*)As;
    {
        float4 t0 = A4[(size_t)row0 * 32 + tid];
        float4 t1 = A4[(size_t)row0 * 32 + tid + 256];
        float s0 = ((tid & 31) < 16) ? inv0 : inv1;   // cols 0-63 = head0
        t0.x *= s0; t0.y *= s0; t0.z *= s0; t0.w *= s0;
        t1.x *= s0; t1.y *= s0; t1.z *= s0; t1.w *= s0;
        As4[tid] = t0; As4[tid + 256] = t1;
    }
    __syncthreads();
    int r = tid >> 4, cg = tid & 15;
    float4 acc = b4[cg];
    const float* a = &As[r * HH];
    for (int k = 0; k < HH; k++) {
        float av = a[k];
        float4 w = W4[k * 16 + cg];
        acc.x += av * w.x; acc.y += av * w.y; acc.z += av * w.z; acc.w += av * w.w;
    }
    X4[(size_t)(row0 + r) * 16 + cg] = acc;
    E4[(size_t)(row0 + r) * 32 + l * 16 + cg] = acc;
}

// ---------------- fused attention conv (both relations; logits+exp+scatter) ----
// wave per dest node; 8 edges in flight (16 lanes x 2 per group); unnormalized
// accumulation; block-partial exp-sums atomically added to sums.
__global__ __launch_bounds__(256) void conv_kernel(
        const int* __restrict__ ptr12, const int* __restrict__ rs12,
        const int* __restrict__ ptr21, const int* __restrict__ rs21,
        const float* __restrict__ Kb, const float* __restrict__ Qb,
        const float* __restrict__ Vb, float* __restrict__ aggb,
        float* __restrict__ sums, int l) {
    int rel = blockIdx.y;
    const int* __restrict__ ptr  = rel ? ptr21 : ptr12;
    const int* __restrict__ rows = rel ? rs21 : rs12;
    const float4* K4 = (const float4*)(Kb + (size_t)rel * NN * HH);
    const float4* Q4 = (const float4*)(Qb + (size_t)rel * NN * HH);
    const float4* V4 = (const float4*)(Vb + (size_t)rel * NN * HH);
    float4* A4 = (float4*)(aggb + (size_t)rel * NN * HH);

    int wave = threadIdx.x >> 6, lane = threadIdx.x & 63;
    int g = lane >> 4, s = lane & 15;
    int c = blockIdx.x * 4 + wave;
    float4 q0 = Q4[(size_t)c * 32 + s];
    float4 q1 = Q4[(size_t)c * 32 + 16 + s];
    float4 acc0 = {0.f, 0.f, 0.f, 0.f}, acc1 = {0.f, 0.f, 0.f, 0.f};
    float ex0 = 0.f, ex1 = 0.f;
    int jb = ptr[c], je = ptr[c + 1];
    int ra = (jb + g     < je) ? rows[jb + g]     : -1;
    int rb = (jb + 4 + g < je) ? rows[jb + 4 + g] : -1;
    for (int j = jb; j < je; j += 8) {
        int na = (j + 8 + g  < je) ? rows[j + 8 + g]  : -1;
        int nb = (j + 12 + g < je) ? rows[j + 12 + g] : -1;
        int rra = (ra >= 0) ? ra : 0;
        int rrb = (rb >= 0) ? rb : 0;
        float4 k0a = K4[(size_t)rra * 32 + s];
        float4 k1a = K4[(size_t)rra * 32 + 16 + s];
        float4 k0b = K4[(size_t)rrb * 32 + s];
        float4 k1b = K4[(size_t)rrb * 32 + 16 + s];
        float4 v0a = V4[(size_t)rra * 32 + s];
        float4 v1a = V4[(size_t)rra * 32 + 16 + s];
        float4 v0b = V4[(size_t)rrb * 32 + s];
        float4 v1b = V4[(size_t)rrb * 32 + 16 + s];
        float p0a = k0a.x * q0.x + k0a.y * q0.y + k0a.z * q0.z + k0a.w * q0.w;
        float p1a = k1a.x * q1.x + k1a.y * q1.y + k1a.z * q1.z + k1a.w * q1.w;
        float p0b = k0b.x * q0.x + k0b.y * q0.y + k0b.z * q0.z + k0b.w * q0.w;
        float p1b = k1b.x * q1.x + k1b.y * q1.y + k1b.z * q1.z + k1b.w * q1.w;
        #pragma unroll
        for (int off = 1; off <= 8; off <<= 1) {
            p0a += __shfl_xor(p0a, off);
            p1a += __shfl_xor(p1a, off);
            p0b += __shfl_xor(p0b, off);
            p1b += __shfl_xor(p1b, off);
        }
        p0a *= 0.125f; p1a *= 0.125f; p0b *= 0.125f; p1b *= 0.125f;
        p0a = p0a > 0.f ? p0a : 0.2f * p0a;
        p1a = p1a > 0.f ? p1a : 0.2f * p1a;
        p0b = p0b > 0.f ? p0b : 0.2f * p0b;
        p1b = p1b > 0.f ? p1b : 0.2f * p1b;
        float e0a = (ra >= 0) ? __expf(p0a) : 0.f;
        float e1a = (ra >= 0) ? __expf(p1a) : 0.f;
        float e0b = (rb >= 0) ? __expf(p0b) : 0.f;
        float e1b = (rb >= 0) ? __expf(p1b) : 0.f;
        acc0.x += e0a * v0a.x + e0b * v0b.x;
        acc0.y += e0a * v0a.y + e0b * v0b.y;
        acc0.z += e0a * v0a.z + e0b * v0b.z;
        acc0.w += e0a * v0a.w + e0b * v0b.w;
        acc1.x += e1a * v1a.x + e1b * v1b.x;
        acc1.y += e1a * v1a.y + e1b * v1b.y;
        acc1.z += e1a * v1a.z + e1b * v1b.z;
        acc1.w += e1a * v1a.w + e1b * v1b.w;
        if (s == 0) { ex0 += e0a + e0b; ex1 += e1a + e1b; }
        ra = na; rb = nb;
    }
    // cross-group reduce (groups hold disjoint edge subsets)
    #pragma unroll
    for (int off = 16; off <= 32; off <<= 1) {
        acc0.x += __shfl_xor(acc0.x, off); acc0.y += __shfl_xor(acc0.y, off);
        acc0.z += __shfl_xor(acc0.z, off); acc0.w += __shfl_xor(acc0.w, off);
        acc1.x += __shfl_xor(acc1.x, off); acc1.y += __shfl_xor(acc1.y, off);
        acc1.z += __shfl_xor(acc1.z, off); acc1.w += __shfl_xor(acc1.w, off);
    }
    if (g == 0) {
        A4[(size_t)c * 32 + s] = acc0;
        A4[(size_t)c * 32 + 16 + s] = acc1;
    }
    float z0 = (s == 0) ? ex0 : 0.f;
    float z1 = (s == 0) ? ex1 : 0.f;
    z0 += __shfl_xor(z0, 16); z0 += __shfl_xor(z0, 32);
    z1 += __shfl_xor(z1, 16); z1 += __shfl_xor(z1, 32);
    __shared__ float sm[4][2];
    if (lane == 0) { sm[wave][0] = z0; sm[wave][1] = z1; }
    __syncthreads();
    if (threadIdx.x < 2) {
        float t = sm[0][threadIdx.x] + sm[1][threadIdx.x]
                + sm[2][threadIdx.x] + sm[3][threadIdx.x];
        atomicAdd(&sums[l * 4 + rel * 2 + threadIdx.x], t);
    }
}

// ---------------- prediction ----------------
__global__ void pred_kernel(const float* __restrict__ Em, const float* __restrict__ Ed,
                            const int* __restrict__ pe, float* out) {
    const float4* Em4 = (const float4*)Em;
    const float4* Ed4 = (const float4*)Ed;
    int pair = blockIdx.x * 16 + (threadIdx.x >> 4);
    int s = threadIdx.x & 15;
    int m = pe[pair], d = pe[NP + pair];
    float4 a0 = Em4[(size_t)m * 32 + s];
    float4 a1 = Em4[(size_t)m * 32 + 16 + s];
    float4 b0 = Ed4[(size_t)d * 32 + s];
    float4 b1 = Ed4[(size_t)d * 32 + 16 + s];
    float p = a0.x * b0.x + a0.y * b0.y + a0.z * b0.z + a0.w * b0.w
            + a1.x * b1.x + a1.y * b1.y + a1.z * b1.z + a1.w * b1.w;
    #pragma unroll
    for (int off = 1; off <= 8; off <<= 1) p += __shfl_xor(p, off);
    if (s == 0) out[pair] = p;
}

// ---------------- host ----------------

extern "C" void kernel_launch(void* const* d_in, const int* in_sizes, int n_in,
                              void* d_out, int out_size, void* d_ws, size_t ws_size,
                              hipStream_t stream) {
    (void)in_sizes; (void)n_in; (void)out_size; (void)ws_size;
    const float* x_n1 = (const float*)d_in[0];
    const float* x_n2 = (const float*)d_in[1];
    const int*   e12  = (const int*)d_in[2];
    const int*   e21  = (const int*)d_in[3];
    const int*   pe   = (const int*)d_in[4];
    const float* Win  = (const float*)d_in[5];
    const float* b_in = (const float*)d_in[6];
    const float* Wk   = (const float*)d_in[7];
    const float* bk   = (const float*)d_in[8];
    const float* Wq   = (const float*)d_in[9];
    const float* bq   = (const float*)d_in[10];
    const float* Wv   = (const float*)d_in[11];
    const float* bv   = (const float*)d_in[12];
    const float* Wout = (const float*)d_in[13];
    const float* bout = (const float*)d_in[14];
    float* out = (float*)d_out;

    char* w = (char*)d_ws;
    auto carve = [&](size_t nbytes) -> void* {
        void* p = (void*)w;
        w += (nbytes + 255) & ~(size_t)255;
        return p;
    };
    float* x1   = (float*)carve((size_t)NN * HD * 4);
    float* x2   = (float*)carve((size_t)NN * HD * 4);
    float* Kb   = (float*)carve((size_t)2 * NN * HH * 4);
    float* Qb   = (float*)carve((size_t)2 * NN * HH * 4);
    float* Vb   = (float*)carve((size_t)2 * NN * HH * 4);
    float* aggb = (float*)carve((size_t)2 * NN * HH * 4);
    float* Em   = (float*)carve((size_t)NN * HH * 4);
    float* Ed   = (float*)carve((size_t)NN * HH * 4);
    float* sums = (float*)carve(256);
    int* cnt    = (int*)carve((size_t)2 * NN * 4);
    int* cur12  = (int*)carve((size_t)NN * 4);
    int* cur21  = (int*)carve((size_t)NN * 4);
    int* ptr12  = (int*)carve((size_t)(NN + 1) * 4);
    int* ptr21  = (int*)carve((size_t)(NN + 1) * 4);
    int* rs12   = (int*)carve((size_t)NE * 4);
    int* rs21   = (int*)carve((size_t)NE * 4);
    int* cnt12 = cnt;
    int* cnt21 = cnt + NN;

    // CSR build
    hipMemsetAsync(cnt, 0, (size_t)2 * NN * 4, stream);
    int eb = (2 * NE + 255) / 256;
    count_kernel<<<eb, 256, 0, stream>>>(e12, e21, cnt12, cnt21);
    scan_kernel<<<2, 1024, 0, stream>>>(cnt12, cnt21, ptr12, ptr21, cur12, cur21);
    fill_kernel<<<eb, 256, 0, stream>>>(e12, e21, cur12, cur21, rs12, rs21);

    // input linears + relu
    in_gemm<<<dim3(NN / 16, 1, 2), 256, 0, stream>>>(x_n1, x_n2, Win, b_in, x1, x2);

    for (int l = 0; l < 2; l++) {
        kqv_gemm<<<dim3(NN / 8, 1, 6), 256, 0, stream>>>(
            x1, x2, Wk, Wq, Wv, bk, bq, bv, Kb, Qb, Vb, sums, l);
        conv_kernel<<<dim3(P1_BLOCKS, 2), 256, 0, stream>>>(
            ptr12, rs12, ptr21, rs21, Kb, Qb, Vb, aggb, sums, l);
        out_gemm<<<dim3(NN / 16, 1, 2), 256, 0, stream>>>(
            aggb, Wout, bout, sums, l, x1, x2, Em, Ed);
    }

    pred_kernel<<<NP / 16, 256, 0, stream>>>(Em, Ed, pe, out);
}

// Round 4
// 411.214 us; speedup vs baseline: 1.0691x; 1.0691x over previous
//
#include <hip/hip_runtime.h>
#include <hip/hip_fp16.h>

#define NN 10000
#define DIN 128
#define HD 64
#define HH 128          // H*HEADS
#define NE 250000
#define NP 100000
#define P1_BLOCKS 2500

// ---------------- CSR build ----------------

__global__ void count_kernel(const int* e12, const int* e21, int* cnt12, int* cnt21) {
    int t = blockIdx.x * blockDim.x + threadIdx.x;
    if (t < NE)            atomicAdd(&cnt12[e12[NE + t]], 1);
    else if (t < 2 * NE)   atomicAdd(&cnt21[e21[NE + (t - NE)]], 1);
}

__global__ void scan_kernel(const int* cnt12, const int* cnt21,
                            int* ptr12, int* ptr21, int* cur12, int* cur21) {
    const int* cnt = blockIdx.x ? cnt21 : cnt12;
    int* ptr = blockIdx.x ? ptr21 : ptr12;
    int* cur = blockIdx.x ? cur21 : cur12;
    const int T = 1024, C = 10;                 // 1024*10 = 10240 >= 10000
    __shared__ int sm[1024];
    int t = threadIdx.x;
    int v[C]; int tot = 0;
    int base = t * C;
    #pragma unroll
    for (int i = 0; i < C; i++) {
        int id = base + i;
        v[i] = (id < NN) ? cnt[id] : 0;
        tot += v[i];
    }
    sm[t] = tot; __syncthreads();
    for (int off = 1; off < T; off <<= 1) {
        int x = (t >= off) ? sm[t - off] : 0;
        __syncthreads();
        sm[t] += x;
        __syncthreads();
    }
    int run = sm[t] - tot;                      // exclusive prefix
    #pragma unroll
    for (int i = 0; i < C; i++) {
        int id = base + i;
        if (id < NN) { ptr[id] = run; cur[id] = run; }
        run += v[i];
    }
    if (t == T - 1) ptr[NN] = run;
}

__global__ void fill_kernel(const int* e12, const int* e21,
                            int* cur12, int* cur21, int* rs12, int* rs21) {
    int t = blockIdx.x * blockDim.x + threadIdx.x;
    if (t < NE) {
        int c = e12[NE + t];
        int p = atomicAdd(&cur12[c], 1);
        rs12[p] = e12[t];
    } else if (t < 2 * NE) {
        int e = t - NE;
        int c = e21[NE + e];
        int p = atomicAdd(&cur21[c], 1);
        rs21[p] = e21[e];
    }
}

// ---------------- GEMMs ----------------

// x = relu(xn @ Win[z] + b_in[z]); [10000,128]@[128,64]
__global__ void in_gemm(const float* __restrict__ xn1, const float* __restrict__ xn2,
                        const float* __restrict__ Win, const float* __restrict__ b_in,
                        float* x1, float* x2) {
    int z = blockIdx.z;
    const float4* A4 = (const float4*)(z ? xn2 : xn1);
    const float4* W4 = (const float4*)(Win + (size_t)z * DIN * HD);
    const float4* b4 = (const float4*)(b_in + (size_t)z * HD);
    float4* O4 = (float4*)(z ? x2 : x1);
    __shared__ float As[16 * DIN];
    int tid = threadIdx.x;
    int row0 = blockIdx.x * 16;
    float4* As4 = (float4*)As;
    As4[tid]       = A4[(size_t)row0 * 32 + tid];
    As4[tid + 256] = A4[(size_t)row0 * 32 + tid + 256];
    __syncthreads();
    int r = tid >> 4, cg = tid & 15;
    float4 acc = b4[cg];
    const float* a = &As[r * DIN];
    for (int k = 0; k < DIN; k++) {
        float av = a[k];
        float4 w = W4[k * 16 + cg];
        acc.x += av * w.x; acc.y += av * w.y; acc.z += av * w.z; acc.w += av * w.w;
    }
    acc.x = fmaxf(acc.x, 0.f); acc.y = fmaxf(acc.y, 0.f);
    acc.z = fmaxf(acc.z, 0.f); acc.w = fmaxf(acc.w, 0.f);
    O4[(size_t)(row0 + r) * 16 + cg] = acc;
}

// K/Q/V for BOTH relations: z in [0,6): rel = z/3, kind = z%3 (0=K 1=Q 2=V)
// Q -> f32 [rel][NN][128]; K,V -> fp16 interleaved KVh [rel][NN][256 halves]
__global__ void kqv_gemm(const float* __restrict__ x1, const float* __restrict__ x2,
                         const float* __restrict__ Wk, const float* __restrict__ Wq,
                         const float* __restrict__ Wv,
                         const float* __restrict__ bk, const float* __restrict__ bq,
                         const float* __restrict__ bv,
                         __half2* KVh2, float* Qb, float* sums, int l) {
    int z = blockIdx.z;
    int rel = z / 3, kind = z - rel * 3;
    if (z == 0 && blockIdx.x == 0 && threadIdx.x < 4) sums[l * 4 + threadIdx.x] = 0.f;
    const float* xsrc = rel ? x2 : x1;
    const float* xdst = rel ? x1 : x2;
    const float* A = (kind == 1) ? xdst : xsrc;
    size_t wo = (size_t)(l * 2 + rel) * HD * HH;
    size_t bo = (size_t)(l * 2 + rel) * HH;
    const float4* W4 = (const float4*)((kind == 0 ? Wk : kind == 1 ? Wq : Wv) + wo);
    const float4* b4 = (const float4*)((kind == 0 ? bk : kind == 1 ? bq : bv) + bo);
    const float4* A4 = (const float4*)A;
    __shared__ float As[8 * HD];
    int tid = threadIdx.x;
    int row0 = blockIdx.x * 8;
    if (tid < 128) ((float4*)As)[tid] = A4[(size_t)row0 * 16 + tid];
    __syncthreads();
    int r = tid >> 5, cg = tid & 31;
    float4 acc = b4[cg];
    const float* a = &As[r * HD];
    for (int k = 0; k < HD; k++) {
        float av = a[k];
        float4 w = W4[k * 32 + cg];
        acc.x += av * w.x; acc.y += av * w.y; acc.z += av * w.z; acc.w += av * w.w;
    }
    int node = row0 + r;
    if (kind == 1) {
        float4* O4 = (float4*)(Qb + (size_t)rel * NN * HH);
        O4[(size_t)node * 32 + cg] = acc;
    } else {
        __half2* H2 = KVh2 + (size_t)rel * NN * 128 + (size_t)node * 128
                    + (kind == 0 ? 0 : 64) + cg * 2;
        float2 lo = {acc.x, acc.y}, hi = {acc.z, acc.w};
        H2[0] = __float22half2_rn(lo);
        H2[1] = __float22half2_rn(hi);
    }
}

// x_new = (agg * softmax_scale) @ Wout + bout; writes x f32 and Em/Ed fp16
__global__ void out_gemm(const float* __restrict__ aggb,
                         const float* __restrict__ Wout, const float* __restrict__ bout,
                         const float* __restrict__ sums, int l,
                         float* x1, float* x2, __half2* Emh2, __half2* Edh2) {
    int z = blockIdx.z;
    int sel = z ? 0 : 1;                        // which relation's aggregate
    const float4* A4 = (const float4*)(aggb + (size_t)sel * NN * HH);
    const float4* W4 = (const float4*)(Wout + (size_t)(l * 2 + z) * HH * HD);
    const float4* b4 = (const float4*)(bout + (size_t)(l * 2 + z) * HD);
    float inv0 = 1.f / sums[l * 4 + sel * 2 + 0];
    float inv1 = 1.f / sums[l * 4 + sel * 2 + 1];
    float4* X4 = (float4*)(z ? x2 : x1);
    __half2* E2 = z ? Edh2 : Emh2;
    __shared__ float As[16 * HH];
    int tid = threadIdx.x;
    int row0 = blockIdx.x * 16;
    float4* As4 = (float4*)As;
    {
        float4 t0 = A4[(size_t)row0 * 32 + tid];
        float4 t1 = A4[(size_t)row0 * 32 + tid + 256];
        float s0 = ((tid & 31) < 16) ? inv0 : inv1;   // cols 0-63 = head0
        t0.x *= s0; t0.y *= s0; t0.z *= s0; t0.w *= s0;
        t1.x *= s0; t1.y *= s0; t1.z *= s0; t1.w *= s0;
        As4[tid] = t0; As4[tid + 256] = t1;
    }
    __syncthreads();
    int r = tid >> 4, cg = tid & 15;
    float4 acc = b4[cg];
    const float* a = &As[r * HH];
    for (int k = 0; k < HH; k++) {
        float av = a[k];
        float4 w = W4[k * 16 + cg];
        acc.x += av * w.x; acc.y += av * w.y; acc.z += av * w.z; acc.w += av * w.w;
    }
    int node = row0 + r;
    X4[(size_t)node * 16 + cg] = acc;
    float2 lo = {acc.x, acc.y}, hi = {acc.z, acc.w};
    E2[(size_t)node * 64 + l * 32 + cg * 2]     = __float22half2_rn(lo);
    E2[(size_t)node * 64 + l * 32 + cg * 2 + 1] = __float22half2_rn(hi);
}

// ---------------- fused attention conv ----------------

__device__ __forceinline__ float dot8(const uint4& k, const float* q) {
    const __half2* h = (const __half2*)&k;
    float2 f0 = __half22float2(h[0]), f1 = __half22float2(h[1]);
    float2 f2 = __half22float2(h[2]), f3 = __half22float2(h[3]);
    return q[0]*f0.x + q[1]*f0.y + q[2]*f1.x + q[3]*f1.y
         + q[4]*f2.x + q[5]*f2.y + q[6]*f3.x + q[7]*f3.y;
}
__device__ __forceinline__ void acc8(const uint4& v, float e, float* acc) {
    const __half2* h = (const __half2*)&v;
    float2 f0 = __half22float2(h[0]), f1 = __half22float2(h[1]);
    float2 f2 = __half22float2(h[2]), f3 = __half22float2(h[3]);
    acc[0] += e*f0.x; acc[1] += e*f0.y; acc[2] += e*f1.x; acc[3] += e*f1.y;
    acc[4] += e*f2.x; acc[5] += e*f2.y; acc[6] += e*f3.x; acc[7] += e*f3.y;
}

// wave per dest node; 16 edges in flight (4 per 16-lane group); lanes 0-7 of
// each group own head0 elems [8s,8s+8), lanes 8-15 head1.
__global__ __launch_bounds__(256) void conv_kernel(
        const int* __restrict__ ptr12, const int* __restrict__ rs12,
        const int* __restrict__ ptr21, const int* __restrict__ rs21,
        const __half2* __restrict__ KVh2, const float* __restrict__ Qb,
        float* __restrict__ aggb, float* __restrict__ sums, int l) {
    int rel = blockIdx.y;
    const int* __restrict__ ptr  = rel ? ptr21 : ptr12;
    const int* __restrict__ rows = rel ? rs21 : rs12;
    const uint4* KV = (const uint4*)KVh2 + (size_t)rel * NN * 32;   // 32 uint4/node
    const float4* Q4 = (const float4*)(Qb + (size_t)rel * NN * HH);
    float4* A4 = (float4*)(aggb + (size_t)rel * NN * HH);

    int wave = threadIdx.x >> 6, lane = threadIdx.x & 63;
    int g = lane >> 4, s = lane & 15;
    int c = blockIdx.x * 4 + wave;
    float q[8];
    {
        float4 qa = Q4[(size_t)c * 32 + 2 * s];
        float4 qb = Q4[(size_t)c * 32 + 2 * s + 1];
        q[0]=qa.x; q[1]=qa.y; q[2]=qa.z; q[3]=qa.w;
        q[4]=qb.x; q[5]=qb.y; q[6]=qb.z; q[7]=qb.w;
    }
    float acc[8] = {0,0,0,0,0,0,0,0};
    float ex = 0.f;
    bool exl = (s == 0) || (s == 8);
    int jb = ptr[c], je = ptr[c + 1];
    int r0 = (jb + g      < je) ? rows[jb + g]      : -1;
    int r1 = (jb + 4 + g  < je) ? rows[jb + 4 + g]  : -1;
    int r2 = (jb + 8 + g  < je) ? rows[jb + 8 + g]  : -1;
    int r3 = (jb + 12 + g < je) ? rows[jb + 12 + g] : -1;
    for (int j = jb; j < je; j += 16) {
        int n0 = (j + 16 + g < je) ? rows[j + 16 + g] : -1;
        int n1 = (j + 20 + g < je) ? rows[j + 20 + g] : -1;
        int n2 = (j + 24 + g < je) ? rows[j + 24 + g] : -1;
        int n3 = (j + 28 + g < je) ? rows[j + 28 + g] : -1;
        size_t b0 = (size_t)(r0 >= 0 ? r0 : 0) * 32;
        size_t b1 = (size_t)(r1 >= 0 ? r1 : 0) * 32;
        size_t b2 = (size_t)(r2 >= 0 ? r2 : 0) * 32;
        size_t b3 = (size_t)(r3 >= 0 ? r3 : 0) * 32;
        uint4 k0 = KV[b0 + s],      k1 = KV[b1 + s];
        uint4 k2 = KV[b2 + s],      k3 = KV[b3 + s];
        uint4 v0 = KV[b0 + 16 + s], v1 = KV[b1 + 16 + s];
        uint4 v2 = KV[b2 + 16 + s], v3 = KV[b3 + 16 + s];
        float p0 = dot8(k0, q), p1 = dot8(k1, q);
        float p2 = dot8(k2, q), p3 = dot8(k3, q);
        #pragma unroll
        for (int off = 1; off <= 4; off <<= 1) {
            p0 += __shfl_xor(p0, off);
            p1 += __shfl_xor(p1, off);
            p2 += __shfl_xor(p2, off);
            p3 += __shfl_xor(p3, off);
        }
        p0 *= 0.125f; p1 *= 0.125f; p2 *= 0.125f; p3 *= 0.125f;
        p0 = p0 > 0.f ? p0 : 0.2f * p0;
        p1 = p1 > 0.f ? p1 : 0.2f * p1;
        p2 = p2 > 0.f ? p2 : 0.2f * p2;
        p3 = p3 > 0.f ? p3 : 0.2f * p3;
        float e0 = (r0 >= 0) ? __expf(p0) : 0.f;
        float e1 = (r1 >= 0) ? __expf(p1) : 0.f;
        float e2 = (r2 >= 0) ? __expf(p2) : 0.f;
        float e3 = (r3 >= 0) ? __expf(p3) : 0.f;
        acc8(v0, e0, acc); acc8(v1, e1, acc);
        acc8(v2, e2, acc); acc8(v3, e3, acc);
        if (exl) ex += e0 + e1 + e2 + e3;
        r0 = n0; r1 = n1; r2 = n2; r3 = n3;
    }
    // cross-group reduce (groups hold disjoint edge subsets)
    #pragma unroll
    for (int i = 0; i < 8; i++) {
        acc[i] += __shfl_xor(acc[i], 16);
        acc[i] += __shfl_xor(acc[i], 32);
    }
    if (g == 0) {
        float4 s0 = {acc[0], acc[1], acc[2], acc[3]};
        float4 s1 = {acc[4], acc[5], acc[6], acc[7]};
        A4[(size_t)c * 32 + 2 * s] = s0;
        A4[(size_t)c * 32 + 2 * s + 1] = s1;
    }
    float zz = ex;
    zz += __shfl_xor(zz, 16);
    zz += __shfl_xor(zz, 32);
    __shared__ float sm[4][2];
    if (lane == 0) sm[wave][0] = zz;
    else if (lane == 8) sm[wave][1] = zz;
    __syncthreads();
    if (threadIdx.x < 2) {
        float t = sm[0][threadIdx.x] + sm[1][threadIdx.x]
                + sm[2][threadIdx.x] + sm[3][threadIdx.x];
        atomicAdd(&sums[l * 4 + rel * 2 + threadIdx.x], t);
    }
}

// ---------------- prediction (fp16 embeddings) ----------------
__global__ void pred_kernel(const __half2* __restrict__ Emh2,
                            const __half2* __restrict__ Edh2,
                            const int* __restrict__ pe, float* out) {
    const uint4* Ea = (const uint4*)Emh2;
    const uint4* Eb = (const uint4*)Edh2;
    int pair = blockIdx.x * 16 + (threadIdx.x >> 4);
    int s = threadIdx.x & 15;
    int m = pe[pair], d = pe[NP + pair];
    uint4 a = Ea[(size_t)m * 16 + s];
    uint4 b = Eb[(size_t)d * 16 + s];
    const __half2* ha = (const __half2*)&a;
    const __half2* hb = (const __half2*)&b;
    float p = 0.f;
    #pragma unroll
    for (int i = 0; i < 4; i++) {
        float2 fa = __half22float2(ha[i]);
        float2 fb = __half22float2(hb[i]);
        p += fa.x * fb.x + fa.y * fb.y;
    }
    #pragma unroll
    for (int off = 1; off <= 8; off <<= 1) p += __shfl_xor(p, off);
    if (s == 0) out[pair] = p;
}

// ---------------- host ----------------

extern "C" void kernel_launch(void* const* d_in, const int* in_sizes, int n_in,
                              void* d_out, int out_size, void* d_ws, size_t ws_size,
                              hipStream_t stream) {
    (void)in_sizes; (void)n_in; (void)out_size; (void)ws_size;
    const float* x_n1 = (const float*)d_in[0];
    const float* x_n2 = (const float*)d_in[1];
    const int*   e12  = (const int*)d_in[2];
    const int*   e21  = (const int*)d_in[3];
    const int*   pe   = (const int*)d_in[4];
    const float* Win  = (const float*)d_in[5];
    const float* b_in = (const float*)d_in[6];
    const float* Wk   = (const float*)d_in[7];
    const float* bk   = (const float*)d_in[8];
    const float* Wq   = (const float*)d_in[9];
    const float* bq   = (const float*)d_in[10];
    const float* Wv   = (const float*)d_in[11];
    const float* bv   = (const float*)d_in[12];
    const float* Wout = (const float*)d_in[13];
    const float* bout = (const float*)d_in[14];
    float* out = (float*)d_out;

    char* w = (char*)d_ws;
    auto carve = [&](size_t nbytes) -> void* {
        void* p = (void*)w;
        w += (nbytes + 255) & ~(size_t)255;
        return p;
    };
    float* x1    = (float*)carve((size_t)NN * HD * 4);
    float* x2    = (float*)carve((size_t)NN * HD * 4);
    float* Qb    = (float*)carve((size_t)2 * NN * HH * 4);
    __half2* KVh2 = (__half2*)carve((size_t)2 * NN * 256 * 2);
    float* aggb  = (float*)carve((size_t)2 * NN * HH * 4);
    __half2* Emh2 = (__half2*)carve((size_t)NN * HH * 2);
    __half2* Edh2 = (__half2*)carve((size_t)NN * HH * 2);
    float* sums  = (float*)carve(256);
    int* cnt     = (int*)carve((size_t)2 * NN * 4);
    int* cur12   = (int*)carve((size_t)NN * 4);
    int* cur21   = (int*)carve((size_t)NN * 4);
    int* ptr12   = (int*)carve((size_t)(NN + 1) * 4);
    int* ptr21   = (int*)carve((size_t)(NN + 1) * 4);
    int* rs12    = (int*)carve((size_t)NE * 4);
    int* rs21    = (int*)carve((size_t)NE * 4);
    int* cnt12 = cnt;
    int* cnt21 = cnt + NN;

    // CSR build
    hipMemsetAsync(cnt, 0, (size_t)2 * NN * 4, stream);
    int eb = (2 * NE + 255) / 256;
    count_kernel<<<eb, 256, 0, stream>>>(e12, e21, cnt12, cnt21);
    scan_kernel<<<2, 1024, 0, stream>>>(cnt12, cnt21, ptr12, ptr21, cur12, cur21);
    fill_kernel<<<eb, 256, 0, stream>>>(e12, e21, cur12, cur21, rs12, rs21);

    // input linears + relu
    in_gemm<<<dim3(NN / 16, 1, 2), 256, 0, stream>>>(x_n1, x_n2, Win, b_in, x1, x2);

    for (int l = 0; l < 2; l++) {
        kqv_gemm<<<dim3(NN / 8, 1, 6), 256, 0, stream>>>(
            x1, x2, Wk, Wq, Wv, bk, bq, bv, KVh2, Qb, sums, l);
        conv_kernel<<<dim3(P1_BLOCKS, 2), 256, 0, stream>>>(
            ptr12, rs12, ptr21, rs21, KVh2, Qb, aggb, sums, l);
        out_gemm<<<dim3(NN / 16, 1, 2), 256, 0, stream>>>(
            aggb, Wout, bout, sums, l, x1, x2, Emh2, Edh2);
    }

    pred_kernel<<<NP / 16, 256, 0, stream>>>(Emh2, Edh2, pe, out);
}